// Round 12
// baseline (165.612 us; speedup 1.0000x reference)
//
#include <hip/hip_runtime.h>
#include <stdint.h>
#include <stddef.h>

// ---------------- types ----------------
typedef __bf16 bf16_t;
typedef bf16_t bf16x4v __attribute__((ext_vector_type(4)));
typedef bf16_t bf16x8v __attribute__((ext_vector_type(8)));
typedef float  f32x4   __attribute__((ext_vector_type(4)));

#define NBATCH 8
#define SEQ    2048
#define DIM    512
#define SP     2052   // padded seq (mult of 12)
#define NB2    1026
#define NB3    684
#define NB4    513
#define NL     512    // output rows per batch (SEQ/4)

static __device__ __forceinline__ f32x4 ldbf4(const bf16_t* p) {
  bf16x4v v = *(const bf16x4v*)p;
  f32x4 r;
  r.x = (float)v[0]; r.y = (float)v[1]; r.z = (float)v[2]; r.w = (float)v[3];
  return r;
}
static __device__ __forceinline__ void stbf4(bf16_t* p, f32x4 v) {
  bf16x4v o;
  o[0] = (bf16_t)v.x; o[1] = (bf16_t)v.y; o[2] = (bf16_t)v.z; o[3] = (bf16_t)v.w;
  *(bf16x4v*)p = o;
}

static __device__ __forceinline__ void gload_lds16(const void* g, void* l) {
  __builtin_amdgcn_global_load_lds(
      (const __attribute__((address_space(1))) void*)g,
      (__attribute__((address_space(3))) void*)l, 16, 0, 0);
}

// ---------------- kPrep: Wt transpose + mask + bias2 --------------------
// G-trick: H[s] = sum_t G[x[s+t]+256t] + bias2, where
//   G[v+256t] = (emb[v] .* dw_w[t]) @ pw   (A' staging fused into kG)
//   bias2[e] = sum_d dwb[d]*pw[d,e] + pwb[e]
#define GP_WT   256                        // 32x32 transpose tiles
#define GP_MASK 65                         // ceil(8*2052/256)
#define GP_B2   2                          // 512 bias2 cols, 256 per block
__global__ __launch_bounds__(256) void kPrep(
    const float* __restrict__ pw, bf16_t* __restrict__ Wt,
    const void* __restrict__ mraw, float* __restrict__ mask01,
    const float* __restrict__ dwb, const float* __restrict__ pwb,
    float* __restrict__ bias2) {
  const int bx = blockIdx.x, t = threadIdx.x;
  if (bx < GP_WT) {
    __shared__ float T[32][33];
    int ti = bx >> 4, tj = bx & 15;
    int r = t >> 3, c0 = (t & 7) * 4;
    f32x4 v = *(const f32x4*)(pw + (size_t)(ti * 32 + r) * DIM + tj * 32 + c0);
    T[c0 + 0][r] = v.x; T[c0 + 1][r] = v.y;
    T[c0 + 2][r] = v.z; T[c0 + 3][r] = v.w;
    __syncthreads();
    bf16x4v o;
    o[0] = (bf16_t)T[r][c0 + 0]; o[1] = (bf16_t)T[r][c0 + 1];
    o[2] = (bf16_t)T[r][c0 + 2]; o[3] = (bf16_t)T[r][c0 + 3];
    *(bf16x4v*)(Wt + (size_t)(tj * 32 + r) * DIM + ti * 32 + c0) = o;
    return;
  }
  if (bx < GP_WT + GP_MASK) {
    int idx = (bx - GP_WT) * 256 + t;
    if (idx >= NBATCH * SP) return;
    int b = idx / SP, s = idx - b * SP;
    const unsigned char* mb = (const unsigned char*)mraw;
    int u8 = 0;
#pragma unroll
    for (int i = 0; i < 64; i++)
      if ((i & 3) != 0 && mb[i] != 0) u8 = 1;
    float v = 0.f;
    if (s < SEQ) {
      int mi = b * SEQ + s;
      int nz = u8 ? (mb[mi] != 0) : (((const int*)mraw)[mi] != 0);
      v = nz ? 1.f : 0.f;
    }
    mask01[idx] = v;
    return;
  }
  // bias2
  {
    int e = (bx - (GP_WT + GP_MASK)) * 256 + t;  // 0..511
    float acc = pwb[e];
#pragma unroll 8
    for (int d = 0; d < DIM; d++) acc += dwb[d] * pw[(size_t)d * DIM + e];
    bias2[e] = acc;
  }
}

// ---------------- kG: G = (emb.*dww)(1024x512) @ Wt^T (bf16 MFMA) -------
// A' staged on the fly: tile rows m0..m0+63 share t_idx = m0>>8 and have
// consecutive v = (m0&255)+r, so A-tile = emb rows * dww[t_idx] directly.
#define BM 64
#define BN 128
#define BK 32
__global__ __launch_bounds__(256) void kG_gemm(
    const float* __restrict__ emb, const float* __restrict__ dww,
    const bf16_t* __restrict__ Bt, bf16_t* __restrict__ G) {
  __shared__ __align__(16) bf16_t As[BM * BK];
  __shared__ __align__(16) bf16_t Bs[BN * BK];
  const int t = threadIdx.x;
  const int mt = blockIdx.x >> 2, nt = blockIdx.x & 3;   // 16 x 4 tiles
  const int m0 = mt * BM, n0 = nt * BN;
  const int t_idx = m0 >> 8, v0 = m0 & 255;
  const int lane = t & 63, wave = t >> 6;
  const int wm = (wave & 1) * 32, wn = (wave >> 1) * 64;
  const int mloc = lane & 15, quad = lane >> 4;

  f32x4 acc[2][4] = {};

  char* bsd1 = (char*)Bs + t * 16;
  char* bsd2 = (char*)Bs + (t + 256) * 16;
  const int ar = t >> 2, ak = (t & 3) * 8;
  const int br2 = (t + 256) >> 2;

  for (int k0 = 0; k0 < 512; k0 += BK) {
    // A-tile: compute emb*dww in regs, cvt bf16, write 16B to LDS
    {
      const float* ep = emb + (size_t)(v0 + ar) * DIM + k0 + ak;
      const float* wp = dww + (size_t)t_idx * DIM + k0 + ak;
      f32x4 e0 = *(const f32x4*)ep, e1 = *(const f32x4*)(ep + 4);
      f32x4 w0 = *(const f32x4*)wp, w1 = *(const f32x4*)(wp + 4);
      f32x4 p0 = e0 * w0, p1 = e1 * w1;
      bf16x8v o;
      o[0] = (bf16_t)p0.x; o[1] = (bf16_t)p0.y;
      o[2] = (bf16_t)p0.z; o[3] = (bf16_t)p0.w;
      o[4] = (bf16_t)p1.x; o[5] = (bf16_t)p1.y;
      o[6] = (bf16_t)p1.z; o[7] = (bf16_t)p1.w;
      *(bf16x8v*)&As[ar * BK + ak] = o;
    }
    gload_lds16(Bt + (size_t)(n0 + ar) * DIM + k0 + ak, bsd1);
    gload_lds16(Bt + (size_t)(n0 + br2) * DIM + k0 + ak, bsd2);
    __syncthreads();
    bf16x8v af[2], bfr[4];
#pragma unroll
    for (int i = 0; i < 2; i++)
      af[i] = *(const bf16x8v*)&As[(wm + i * 16 + mloc) * BK + quad * 8];
#pragma unroll
    for (int i = 0; i < 4; i++)
      bfr[i] = *(const bf16x8v*)&Bs[(wn + i * 16 + mloc) * BK + quad * 8];
#pragma unroll
    for (int mi = 0; mi < 2; mi++)
#pragma unroll
      for (int ni = 0; ni < 4; ni++)
        acc[mi][ni] = __builtin_amdgcn_mfma_f32_16x16x32_bf16(
            af[mi], bfr[ni], acc[mi][ni], 0, 0, 0);
    __syncthreads();
  }
#pragma unroll
  for (int ni = 0; ni < 4; ni++) {
    int col = n0 + wn + ni * 16 + mloc;
#pragma unroll
    for (int mi = 0; mi < 2; mi++) {
      int rbase = m0 + wm + mi * 16 + quad * 4;
#pragma unroll
      for (int r = 0; r < 4; r++)
        G[(size_t)(rbase + r) * DIM + col] = (bf16_t)acc[mi][ni][r];
    }
  }
}

// ---- kBH: build H rows from G-gather + level means + score softmax -> P
__global__ __launch_bounds__(128) void kBH_levels(
    const int* __restrict__ x, const bf16_t* __restrict__ G,
    const float* __restrict__ bias2, const float* __restrict__ mask01,
    const float* __restrict__ sw, const float* __restrict__ sbp,
    bf16_t* __restrict__ R2, bf16_t* __restrict__ R3, bf16_t* __restrict__ R4,
    float* __restrict__ P) {
  const int b = blockIdx.x, c = blockIdx.y;   // c: 0..170
  const int s0 = c * 12;
  const int t = threadIdx.x;
  const int d0 = t * 4;
  const float sb = sbp[0];
  __shared__ int xs[15];
  if (t < 15) {
    int sidx = s0 + t;
    xs[t] = (sidx < SEQ) ? x[b * SEQ + sidx] : -1;
  }
  __syncthreads();

  f32x4 b2 = *(const f32x4*)(bias2 + d0);
  f32x4 h[12];
  float ms[12], p[12];
  f32x4 swv = *(const f32x4*)(sw + d0);
#pragma unroll
  for (int i = 0; i < 12; i++) {
    int s = s0 + i;
    ms[i] = mask01[b * SP + s];
    if (s < SEQ) {
      f32x4 acc = b2;
#pragma unroll
      for (int tt = 0; tt < 4; tt++) {
        int xv = xs[i + tt];
        if (xv >= 0)
          acc += ldbf4(G + (size_t)(xv + 256 * tt) * DIM + d0);
      }
      h[i] = acc;
    } else {
      h[i].x = h[i].y = h[i].z = h[i].w = 0.f;
    }
    p[i] = h[i].x * swv.x + h[i].y * swv.y + h[i].z * swv.z + h[i].w * swv.w;
  }
#pragma unroll
  for (int j = 0; j < 6; j++) {
    int i0 = 2 * j;
    float cc = ms[i0] + ms[i0 + 1];
    f32x4 sm = h[i0] * ms[i0] + h[i0 + 1] * ms[i0 + 1];
    float sc = cc > 0.f ? 1.f / cc : 0.f;
    stbf4(R2 + ((size_t)b * NB2 + (c * 6 + j)) * DIM + d0, sm * sc);
  }
#pragma unroll
  for (int j = 0; j < 4; j++) {
    int i0 = 3 * j;
    float cc = ms[i0] + ms[i0 + 1] + ms[i0 + 2];
    f32x4 sm = h[i0] * ms[i0] + h[i0 + 1] * ms[i0 + 1] + h[i0 + 2] * ms[i0 + 2];
    float sc = cc > 0.f ? 1.f / cc : 0.f;
    stbf4(R3 + ((size_t)b * NB3 + (c * 4 + j)) * DIM + d0, sm * sc);
  }
#pragma unroll
  for (int j = 0; j < 3; j++) {
    int i0 = 4 * j;
    float cc = ms[i0] + ms[i0 + 1] + ms[i0 + 2] + ms[i0 + 3];
    f32x4 sm = h[i0] * ms[i0] + h[i0 + 1] * ms[i0 + 1] +
               h[i0 + 2] * ms[i0 + 2] + h[i0 + 3] * ms[i0 + 3];
    float sc = cc > 0.f ? 1.f / cc : 0.f;
    stbf4(R4 + ((size_t)b * NB4 + (c * 3 + j)) * DIM + d0, sm * sc);
  }
#pragma unroll
  for (int off = 32; off > 0; off >>= 1)
#pragma unroll
    for (int i = 0; i < 12; i++) p[i] += __shfl_down(p[i], off);
  __shared__ float hsw[2][12];
  int lane = t & 63, wv = t >> 6;
  if (lane == 0)
#pragma unroll
    for (int i = 0; i < 12; i++) hsw[wv][i] = p[i];
  __syncthreads();
#define HSUM(i) (hsw[0][i] + hsw[1][i])
  if (t < 12) {
    int i = t;
    float m1 = ms[i];
    float v1 = HSUM(i) * m1 + sb;
    int i2 = i & ~1;
    float cc2 = ms[i2] + ms[i2 + 1];
    float s2 = HSUM(i2) * ms[i2] + HSUM(i2 + 1) * ms[i2 + 1];
    float v2 = (cc2 > 0.f ? s2 / cc2 : 0.f) + sb;
    int i3 = (i >= 9) ? 9 : (i >= 6) ? 6 : (i >= 3) ? 3 : 0;
    float cc3 = ms[i3] + ms[i3 + 1] + ms[i3 + 2];
    float s3 = HSUM(i3) * ms[i3] + HSUM(i3 + 1) * ms[i3 + 1] +
               HSUM(i3 + 2) * ms[i3 + 2];
    float v3 = (cc3 > 0.f ? s3 / cc3 : 0.f) + sb;
    int i4 = i & ~3;
    float cc4 = ms[i4] + ms[i4 + 1] + ms[i4 + 2] + ms[i4 + 3];
    float s4 = HSUM(i4) * ms[i4] + HSUM(i4 + 1) * ms[i4 + 1] +
               HSUM(i4 + 2) * ms[i4 + 2] + HSUM(i4 + 3) * ms[i4 + 3];
    float v4 = (cc4 > 0.f ? s4 / cc4 : 0.f) + sb;
    const float NEG = -3.0e38f;
    float a1 = m1 > 0.f ? v1 : NEG, a2 = cc2 > 0.f ? v2 : NEG;
    float a3 = cc3 > 0.f ? v3 : NEG, a4 = cc4 > 0.f ? v4 : NEG;
    float mx = fmaxf(fmaxf(a1, a2), fmaxf(a3, a4));
    f32x4 o;
    if (mx <= NEG) {
      o.x = o.y = o.z = o.w = 0.25f;
    } else {
      float e1 = m1 > 0.f ? __expf(v1 - mx) : 0.f;
      float e2 = cc2 > 0.f ? __expf(v2 - mx) : 0.f;
      float e3 = cc3 > 0.f ? __expf(v3 - mx) : 0.f;
      float e4 = cc4 > 0.f ? __expf(v4 - mx) : 0.f;
      float inv = 1.f / (e1 + e2 + e3 + e4);
      o.x = e1 * inv; o.y = e2 * inv; o.z = e3 * inv; o.w = e4 * inv;
    }
    *(f32x4*)(P + ((size_t)b * SP + s0 + i) * 4) = o;
  }
#undef HSUM
}

// ---- k56 v3: fused seq attention + output --------------------------------
// SoA stride-1 LDS (conflict-free; v2's 16B-stride AoS was 8-way-conflicted)
// + 4 queries per LDS read: each wave processes its 4 rows against one
// staged p_j (4x ILP, 4x less LDS traffic). LQ=2112=33*64; rows >=SP zeroed
// and counted in nmv (exp(0)=1 correction exact).
#define LQ 2112
__global__ __launch_bounds__(256) void k56_attn_out(
    const float* __restrict__ P, const float* __restrict__ mask01,
    const int* __restrict__ x, const bf16_t* __restrict__ G,
    const float* __restrict__ bias2, const bf16_t* __restrict__ R2,
    const bf16_t* __restrict__ R3, const bf16_t* __restrict__ R4,
    float* __restrict__ out, float* __restrict__ omask) {
  __shared__ float Qx[LQ], Qy[LQ], Qz[LQ], Qw[LQ];   // 33792 B
  __shared__ f32x4 ws4[16];
  __shared__ float msk[16];
  __shared__ float c4w[4];
  __shared__ int xs[20];
  const int b = blockIdx.x, lbase = blockIdx.y * 4;   // 4 l's per block
  const int t = threadIdx.x;
  const int w = t >> 6, lane = t & 63;
  const int smin = lbase * 4;              // 16 s-rows per block

  if (t < 20) {
    int sidx = smin + t;
    xs[t] = (sidx < SEQ) ? x[b * SEQ + sidx] : -1;
  }
  // stage P[b] SoA; zero masked + pad rows (counted in nmv)
  float cnt0 = 0.f;
#pragma unroll
  for (int it = 0; it < 9; it++) {
    int j = it * 256 + t;
    if (j >= LQ) break;
    f32x4 q; q.x = q.y = q.z = q.w = 0.f;
    if (j < SP) {
      float mf = mask01[b * SP + j];
      if (mf != 0.f) {
        q = *(const f32x4*)(P + ((size_t)b * SP + j) * 4);
      } else {
        cnt0 += 1.f;
      }
    } else {
      cnt0 += 1.f;
    }
    Qx[j] = q.x; Qy[j] = q.y; Qz[j] = q.z; Qw[j] = q.w;
  }
#pragma unroll
  for (int off = 32; off > 0; off >>= 1) cnt0 += __shfl_down(cnt0, off);
  if (lane == 0) c4w[w] = cnt0;
  __syncthreads();
  const float nmv = c4w[0] + c4w[1] + c4w[2] + c4w[3];

  // attention: wave w processes its 4 rows (sl = w*4..w*4+3) together
  {
    int s0q = smin + w * 4;
    f32x4 q0, q1, q2, q3;
    q0.x = Qx[s0q + 0]; q0.y = Qy[s0q + 0]; q0.z = Qz[s0q + 0]; q0.w = Qw[s0q + 0];
    q1.x = Qx[s0q + 1]; q1.y = Qy[s0q + 1]; q1.z = Qz[s0q + 1]; q1.w = Qw[s0q + 1];
    q2.x = Qx[s0q + 2]; q2.y = Qy[s0q + 2]; q2.z = Qz[s0q + 2]; q2.w = Qw[s0q + 2];
    q3.x = Qx[s0q + 3]; q3.y = Qy[s0q + 3]; q3.z = Qz[s0q + 3]; q3.w = Qw[s0q + 3];
    f32x4 ac0, ac1, ac2, ac3;
    ac0.x = ac0.y = ac0.z = ac0.w = 0.f; ac1 = ac0; ac2 = ac0; ac3 = ac0;
    float dn0 = 0.f, dn1 = 0.f, dn2 = 0.f, dn3 = 0.f;
#pragma unroll 1
    for (int it = 0; it < LQ / 64; it++) {
      int jb = it * 64 + lane;
      float px = Qx[jb], py = Qy[jb], pz = Qz[jb], pw4 = Qw[jb];
      float e0 = __expf(q0.x * px + q0.y * py + q0.z * pz + q0.w * pw4);
      float e1 = __expf(q1.x * px + q1.y * py + q1.z * pz + q1.w * pw4);
      float e2 = __expf(q2.x * px + q2.y * py + q2.z * pz + q2.w * pw4);
      float e3 = __expf(q3.x * px + q3.y * py + q3.z * pz + q3.w * pw4);
      dn0 += e0; ac0.x += e0 * px; ac0.y += e0 * py; ac0.z += e0 * pz; ac0.w += e0 * pw4;
      dn1 += e1; ac1.x += e1 * px; ac1.y += e1 * py; ac1.z += e1 * pz; ac1.w += e1 * pw4;
      dn2 += e2; ac2.x += e2 * px; ac2.y += e2 * py; ac2.z += e2 * pz; ac2.w += e2 * pw4;
      dn3 += e3; ac3.x += e3 * px; ac3.y += e3 * py; ac3.z += e3 * pz; ac3.w += e3 * pw4;
    }
#pragma unroll
    for (int off = 32; off > 0; off >>= 1) {
      ac0.x += __shfl_down(ac0.x, off); ac0.y += __shfl_down(ac0.y, off);
      ac0.z += __shfl_down(ac0.z, off); ac0.w += __shfl_down(ac0.w, off);
      dn0 += __shfl_down(dn0, off);
      ac1.x += __shfl_down(ac1.x, off); ac1.y += __shfl_down(ac1.y, off);
      ac1.z += __shfl_down(ac1.z, off); ac1.w += __shfl_down(ac1.w, off);
      dn1 += __shfl_down(dn1, off);
      ac2.x += __shfl_down(ac2.x, off); ac2.y += __shfl_down(ac2.y, off);
      ac2.z += __shfl_down(ac2.z, off); ac2.w += __shfl_down(ac2.w, off);
      dn2 += __shfl_down(dn2, off);
      ac3.x += __shfl_down(ac3.x, off); ac3.y += __shfl_down(ac3.y, off);
      ac3.z += __shfl_down(ac3.z, off); ac3.w += __shfl_down(ac3.w, off);
      dn3 += __shfl_down(dn3, off);
    }
    if (lane == 0) {
#pragma unroll
      for (int k = 0; k < 4; k++) {
        f32x4 acc = (k == 0) ? ac0 : (k == 1) ? ac1 : (k == 2) ? ac2 : ac3;
        float den = (k == 0) ? dn0 : (k == 1) ? dn1 : (k == 2) ? dn2 : dn3;
        den -= nmv;
        float inv = den > 0.f ? 1.f / den : 0.f;
        f32x4 wv4; wv4.x = acc.x * inv; wv4.y = acc.y * inv;
        wv4.z = acc.z * inv; wv4.w = acc.w * inv;
        int sl = w * 4 + k;
        ws4[sl] = wv4;
        msk[sl] = mask01[b * SP + smin + sl];
      }
    }
  }
  __syncthreads();

  // output: 4 l's, 2 per pass (128 threads each); r1 from G-gather
  const int d0 = (t & 127) * 4;
  const f32x4 b2 = *(const f32x4*)(bias2 + d0);
#pragma unroll 1
  for (int p = 0; p < 2; p++) {
    int ll = p * 2 + (t >> 7);             // local l 0..3
    int l = lbase + ll;
    f32x4 o; o.x = o.y = o.z = o.w = 0.f;
    float cnt = 0.f;
#pragma unroll
    for (int si = 0; si < 4; si++) {
      int sl = ll * 4 + si;
      int s = l * 4 + si;
      float m = msk[sl];
      f32x4 wv4 = ws4[sl];
      f32x4 r1 = b2;
#pragma unroll
      for (int tt = 0; tt < 4; tt++) {
        int xv = xs[sl + tt];
        if (xv >= 0)
          r1 += ldbf4(G + (size_t)(xv + 256 * tt) * DIM + d0);
      }
      f32x4 r2 = ldbf4(R2 + ((size_t)b * NB2 + (s >> 1)) * DIM + d0);
      f32x4 r3 = ldbf4(R3 + ((size_t)b * NB3 + (s / 3)) * DIM + d0);
      f32x4 r4 = ldbf4(R4 + ((size_t)b * NB4 + (s >> 2)) * DIM + d0);
      o += m * (wv4.x * r1 + wv4.y * r2 + wv4.z * r3 + wv4.w * r4);
      cnt += m;
    }
    float inv = cnt > 0.f ? 1.f / cnt : 0.f;
    o *= inv;
    *(f32x4*)(out + ((size_t)b * NL + l) * DIM + d0) = o;
    if ((t & 127) == 0) omask[b * NL + l] = cnt > 0.f ? 1.f : 0.f;
  }
}

// ---------------- launch ----------------
extern "C" void kernel_launch(void* const* d_in, const int* in_sizes, int n_in,
                              void* d_out, int out_size, void* d_ws, size_t ws_size,
                              hipStream_t stream) {
  const int*   x    = (const int*)d_in[0];
  const void*  mraw = d_in[1];
  const float* emb  = (const float*)d_in[2];
  const float* dww  = (const float*)d_in[3];
  const float* dwb  = (const float*)d_in[4];
  const float* pw   = (const float*)d_in[5];
  const float* pwb  = (const float*)d_in[6];
  const float* sw   = (const float*)d_in[7];
  const float* sb   = (const float*)d_in[8];

  char* ws = (char*)d_ws;
  size_t off = 0;
  auto alloc = [&](size_t bytes) {
    size_t o = off;
    off = (off + bytes + 255) & ~(size_t)255;
    return o;
  };
  bf16_t* G    = (bf16_t*)(ws + alloc((size_t)1024 * DIM * 2));
  bf16_t* Wt   = (bf16_t*)(ws + alloc((size_t)DIM * DIM * 2));
  float* bias2 = (float*)(ws + alloc((size_t)DIM * 4));
  bf16_t* R2   = (bf16_t*)(ws + alloc((size_t)NBATCH * NB2 * DIM * 2));
  bf16_t* R3   = (bf16_t*)(ws + alloc((size_t)NBATCH * NB3 * DIM * 2));
  bf16_t* R4   = (bf16_t*)(ws + alloc((size_t)NBATCH * NB4 * DIM * 2));
  float* mask01 = (float*)(ws + alloc((size_t)NBATCH * SP * 4));
  float* P     = (float*)(ws + alloc((size_t)NBATCH * SP * 4 * 4));

  float* out   = (float*)d_out;
  float* omask = out + (size_t)NBATCH * NL * DIM;

  kPrep<<<GP_WT + GP_MASK + GP_B2, 256, 0, stream>>>(
      pw, Wt, mraw, mask01, dwb, pwb, bias2);
  kG_gemm<<<64, 256, 0, stream>>>(emb, dww, Wt, G);
  kBH_levels<<<dim3(NBATCH, 171), 128, 0, stream>>>(x, G, bias2, mask01,
                                                    sw, sb, R2, R3, R4, P);
  k56_attn_out<<<dim3(NBATCH, 128), 256, 0, stream>>>(P, mask01, x, G, bias2,
                                                      R2, R3, R4, out, omask);
}